// Round 2
// baseline (105.434 us; speedup 1.0000x reference)
//
#include <hip/hip_runtime.h>

// Problem constants (from reference setup_inputs)
#define BB 64
#define NN 128
#define DD 128
#define AA 1000
#define KPAD 1024
#define NEG_INF (-9.0e15f)

typedef __attribute__((ext_vector_type(8))) short short8;   // 8 bf16 MFMA frag
typedef __attribute__((ext_vector_type(4))) float floatx4;  // MFMA C/D frag
typedef __attribute__((ext_vector_type(4))) unsigned int uintx4;
typedef __attribute__((ext_vector_type(2))) unsigned int uintx2;

__device__ __forceinline__ float bflo(unsigned int u) { return __uint_as_float(u << 16); }
__device__ __forceinline__ float bfhi(unsigned int u) { return __uint_as_float(u & 0xffff0000u); }
// truncating fp32->bf16 pack (cheap; ~2^-9 rel bias, fine vs threshold)
__device__ __forceinline__ unsigned int packbf(float f0, float f1) {
  return (__float_as_uint(f0) >> 16) | (__float_as_uint(f1) & 0xffff0000u);
}
// round-to-nearest-even fp32->bf16
__device__ __forceinline__ unsigned short bf_rne(float f) {
  unsigned int u = __float_as_uint(f);
  return (unsigned short)((u + 0x7fffu + ((u >> 16) & 1u)) >> 16);
}
__device__ __forceinline__ unsigned int packbf_rne(float f0, float f1) {
  return (unsigned int)bf_rne(f0) | ((unsigned int)bf_rne(f1) << 16);
}
__device__ __forceinline__ short8 u2s(uintx4 v) {
  union { uintx4 u; short8 s; } x; x.u = v; return x.s;
}

// ---------------------------------------------------------------------------
// Prep (96 blocks x 256):
//   blocks 0..63  -> HTg[b][d][i] = bf16(h[b]^T)  AND  Hg[b] = bf16(h[b]) in
//                    the exact (swizzled) linear layout attn's Hs uses, so the
//                    fused kernel stages Hs with a plain 16B/lane copy.
//   blocks 64..95 -> ET[c][k] = bf16(emb[k][c]) via coalesced rows + LDS
//                    transpose, k zero-padded to 1024.
// ---------------------------------------------------------------------------
__global__ __launch_bounds__(256) void prep_kernel(
    const float* __restrict__ hidden, const float* __restrict__ emb,
    unsigned short* __restrict__ ET, unsigned short* __restrict__ HTg,
    unsigned short* __restrict__ Hg)
{
  __shared__ float hsf[NN * 129];
  const int t = threadIdx.x;
  const int bid = blockIdx.x;
  if (bid < BB) {
    const float* hb = hidden + (size_t)bid * NN * DD;
    #pragma unroll
    for (int u = 0; u < 16; ++u) {
      int e = u * 1024 + t * 4;
      float4 v = *reinterpret_cast<const float4*>(hb + e);
      int r = e >> 7, c = e & 127;
      float* d = &hsf[r * 129 + c];
      d[0] = v.x; d[1] = v.y; d[2] = v.z; d[3] = v.w;
    }
    __syncthreads();
    unsigned short* ht16 = HTg + (size_t)bid * NN * DD;
    #pragma unroll
    for (int u = 0; u < 8; ++u) {  // transpose via LDS columns
      int e = u * 2048 + t * 8;
      int dI = e >> 7, il = e & 127;
      float x[8];
      #pragma unroll
      for (int j = 0; j < 8; ++j) x[j] = hsf[(il + j) * 129 + dI];
      uintx4 o;
      o.x = packbf_rne(x[0], x[1]); o.y = packbf_rne(x[2], x[3]);
      o.z = packbf_rne(x[4], x[5]); o.w = packbf_rne(x[6], x[7]);
      *reinterpret_cast<uintx4*>(ht16 + e) = o;
    }
    // Hg: row-major bf16 h, pre-swizzled (c ^ (r&15)) to match Hs layout
    unsigned short* hg = Hg + (size_t)bid * NN * DD;
    #pragma unroll
    for (int u = 0; u < 8; ++u) {
      int id = u * 256 + t;
      int r = id >> 4, c = id & 15;
      const float* src = &hsf[r * 129 + c * 8];
      uintx4 o;
      o.x = packbf_rne(src[0], src[1]); o.y = packbf_rne(src[2], src[3]);
      o.z = packbf_rne(src[4], src[5]); o.w = packbf_rne(src[6], src[7]);
      *reinterpret_cast<uintx4*>(&hg[r * 128 + ((c ^ (r & 15)) << 3)]) = o;
    }
  } else {
    // ET transpose: 32 blocks, 32 k-rows each, coalesced emb reads.
    const int k0 = (bid - BB) * 32;
    #pragma unroll
    for (int u = 0; u < 4; ++u) {
      int e = u * 1024 + t * 4;
      int r = e >> 7, c = e & 127;
      float4 z = {0.f, 0.f, 0.f, 0.f};
      float4 v = (k0 + r < AA)
          ? *reinterpret_cast<const float4*>(emb + (size_t)(k0 + r) * DD + c) : z;
      float* d = &hsf[r * 129 + c];
      d[0] = v.x; d[1] = v.y; d[2] = v.z; d[3] = v.w;
    }
    __syncthreads();
    int c = t >> 1, j0 = (t & 1) * 16;
    float x[16];
    #pragma unroll
    for (int j = 0; j < 16; ++j) x[j] = hsf[(j0 + j) * 129 + c];
    uintx4 o0, o1;
    o0.x = packbf_rne(x[0], x[1]);  o0.y = packbf_rne(x[2], x[3]);
    o0.z = packbf_rne(x[4], x[5]);  o0.w = packbf_rne(x[6], x[7]);
    o1.x = packbf_rne(x[8], x[9]);  o1.y = packbf_rne(x[10], x[11]);
    o1.z = packbf_rne(x[12], x[13]); o1.w = packbf_rne(x[14], x[15]);
    unsigned short* dst = ET + (size_t)c * KPAD + k0 + j0;
    *reinterpret_cast<uintx4*>(dst) = o0;
    *reinterpret_cast<uintx4*>(dst + 8) = o1;
  }
}

// ---------------------------------------------------------------------------
// Fused kernel, grid = 768 = exactly 3 blocks/CU (LDS 53248 B), zero tail.
// Single-phase blocks: wid%3==2 -> one 32-row attr-GEMM tile (256 blocks);
// else one 16-row attn tile (512 blocks). Each CU hosts ~2 attn + 1 attr,
// so Aattr HBM streaming overlaps the LDS/L2-bound attn phases machine-wide
// WITHOUT serializing both phases on one block's critical path.
// As is halved (one edge-type PAIR at a time, two passes) to fit 3/CU; the
// doubled B-frag reads are cancelled by hoisting the 8 unique Hs B-frags
// into registers (hvq) once.
// ---------------------------------------------------------------------------
struct AttnSmem {
  __align__(16) unsigned short Hs[NN * 128];        // 32768 B bf16 h (swizzled)
  union {
    __align__(16) unsigned short As[2 * 16 * 256];  // 16384 B (QK, one k-pair)
    struct {
      __align__(16) float Sa[16 * 129];             // 8256 B (post-QK)
      __align__(16) unsigned short W[16 * 128];     // 4096 B (softmax out)
    } sw;
  } u2;
  __align__(16) float saf[4 * 256];                 // 4096 B scale table
};  // 53248 B

#define BK 64
struct AttrSmem {
  __align__(16) unsigned short ETs[2][DD * BK];     // 32768 B
  __align__(16) unsigned short As2[2][32 * BK];     // 8192 B (32-row tile)
};  // 40960 B

union FusedSmem { AttnSmem a; AttrSmem g; };        // 53248 B -> 3 blocks/CU

__device__ __forceinline__ void attn_body(
    AttnSmem& s, const int* __restrict__ adj, const float* __restrict__ amat,
    const unsigned short* __restrict__ Hg, const unsigned short* __restrict__ HTg,
    float* __restrict__ out0, int tile)
{
  const int t = threadIdx.x;
  const int L = t & 63, w = t >> 6;     // wave w = j-quarter / d-quarter
  const int lr = L & 15, lq = L >> 4;   // MFMA lane coords
  const int b = tile >> 3;
  const int i0 = (tile & 7) * 16;

  // ---- prefetch adj (in flight under staging) ----
  const int* adjb = adj + ((size_t)b * NN + i0) * NN;
  int adjv[8];
  #pragma unroll
  for (int nt = 0; nt < 2; ++nt)
    #pragma unroll
    for (int r = 0; r < 4; ++r)
      adjv[nt * 4 + r] = adjb[(lq * 4 + r) * NN + w * 32 + nt * 16 + lr];

  // ---- stage Hs: linear 16B/lane copy (Hg is pre-swizzled bf16) ----
  const unsigned short* hg = Hg + (size_t)b * NN * DD;
  #pragma unroll
  for (int u = 0; u < 8; ++u) {
    int id = u * 256 + t;
    *reinterpret_cast<uintx4*>(&s.Hs[id * 8]) =
        *reinterpret_cast<const uintx4*>(hg + id * 8);
  }
  // ---- scale table: saf[k][d]=0.6*a[d][k], saf[k][128+d]=0.4*a[d][k] ----
  {
    float v1 = amat[t], v2 = amat[t + 256];
    int dI = t >> 2, k = t & 3;
    s.saf[k * 256 + dI] = 0.6f * v1;
    s.saf[k * 256 + 128 + dI] = 0.4f * v1;
    s.saf[k * 256 + 64 + dI] = 0.6f * v2;
    s.saf[k * 256 + 192 + dI] = 0.4f * v2;
  }
  __syncthreads();

  // ---- hoist the 8 unique QK B-frags (reused across both k-pair passes) ----
  uintx4 hvq[2][4];
  #pragma unroll
  for (int nt = 0; nt < 2; ++nt)
    #pragma unroll
    for (int q = 0; q < 4; ++q) {
      int jrow = w * 32 + nt * 16 + lr;
      hvq[nt][q] = *reinterpret_cast<const uintx4*>(
          &s.Hs[jrow * 128 + (((lq + 4 * q) ^ (jrow & 15)) << 3)]);
    }

  floatx4 acc[4][2];
  #pragma unroll
  for (int k = 0; k < 4; ++k)
    #pragma unroll
    for (int nt = 0; nt < 2; ++nt) acc[k][nt] = floatx4{0.f, 0.f, 0.f, 0.f};

  // ---- QK in two k-pair passes (As holds 2 edge types at a time) ----
  #pragma unroll
  for (int kp = 0; kp < 2; ++kp) {
    if (kp) __syncthreads();  // pass-0 As reads complete before overwrite
    // build As[kk][i][d'] (d'<128: h*0.6a_k ; d'>=128: |h|*0.4a_k)
    #pragma unroll
    for (int u = 0; u < 4; ++u) {
      int id = u * 256 + t;
      int kk = id >> 9, ii = (id >> 5) & 15, c = id & 31;
      int srow = i0 + ii;
      int dchunk = c & 15;
      uintx4 hv = *reinterpret_cast<const uintx4*>(
          &s.Hs[srow * 128 + ((dchunk ^ (srow & 15)) << 3)]);
      if (c & 16) {
        hv.x &= 0x7fff7fffu; hv.y &= 0x7fff7fffu;
        hv.z &= 0x7fff7fffu; hv.w &= 0x7fff7fffu;
      }
      const float* sf = &s.saf[(kp * 2 + kk) * 256 + c * 8];
      uintx4 o;
      o.x = packbf(bflo(hv.x) * sf[0], bfhi(hv.x) * sf[1]);
      o.y = packbf(bflo(hv.y) * sf[2], bfhi(hv.y) * sf[3]);
      o.z = packbf(bflo(hv.z) * sf[4], bfhi(hv.z) * sf[5]);
      o.w = packbf(bflo(hv.w) * sf[6], bfhi(hv.w) * sf[7]);
      *reinterpret_cast<uintx4*>(&s.u2.As[kk * 4096 + ii * 256 + ((c ^ ii) << 3)]) = o;
    }
    __syncthreads();

    #pragma unroll
    for (int kt = 0; kt < 8; ++kt) {
      int ca = lq + 4 * kt;
      short8 afr[2];
      #pragma unroll
      for (int kk = 0; kk < 2; ++kk)
        afr[kk] = *reinterpret_cast<const short8*>(
            &s.u2.As[kk * 4096 + lr * 256 + ((ca ^ lr) << 3)]);
      #pragma unroll
      for (int nt = 0; nt < 2; ++nt) {
        uintx4 hv = hvq[nt][kt & 3];
        if (kt >= 4) {
          hv.x &= 0x7fff7fffu; hv.y &= 0x7fff7fffu;
          hv.z &= 0x7fff7fffu; hv.w &= 0x7fff7fffu;
        }
        short8 bfr = u2s(hv);
        #pragma unroll
        for (int kk = 0; kk < 2; ++kk)
          acc[kp * 2 + kk][nt] = __builtin_amdgcn_mfma_f32_16x16x32_bf16(
              afr[kk], bfr, acc[kp * 2 + kk][nt], 0, 0, 0);
      }
    }
  }
  __syncthreads();  // all As reads done; Sa/W may now overlay As

  // ---- prefetch PV B-frags from HTg (hides under selection/softmax) ----
  short8 pvb[2][4];
  const unsigned short* ht = HTg + (size_t)b * NN * DD;
  #pragma unroll
  for (int nt = 0; nt < 2; ++nt)
    #pragma unroll
    for (int kt = 0; kt < 4; ++kt) {
      int dI = w * 32 + nt * 16 + lr;
      pvb[nt][kt] = *reinterpret_cast<const short8*>(ht + dI * 128 + kt * 32 + lq * 8);
    }

  // ---- in-register adj selection; C/D: col=lane&15, row=(lane>>4)*4+reg ----
  #pragma unroll
  for (int nt = 0; nt < 2; ++nt)
    #pragma unroll
    for (int r = 0; r < 4; ++r) {
      int ii = lq * 4 + r;
      int j = w * 32 + nt * 16 + lr;
      int ad = adjv[nt * 4 + r];
      float al = NEG_INF;
      al = (ad == 1) ? acc[0][nt][r] : al;
      al = (ad == 2) ? acc[1][nt][r] : al;
      al = (ad == 3) ? acc[2][nt][r] : al;
      al = (ad == 4) ? acc[3][nt][r] : al;
      s.u2.sw.Sa[ii * 129 + j] = al;
    }
  __syncthreads();

  // ---- softmax: one full row per wave (lane holds j=L and j=L+64) ----
  #pragma unroll
  for (int p = 0; p < 4; ++p) {
    int ii = w * 4 + p;
    float a1 = s.u2.sw.Sa[ii * 129 + L];
    float a2 = s.u2.sw.Sa[ii * 129 + 64 + L];
    float m = fmaxf(a1, a2);
    #pragma unroll
    for (int off = 32; off > 0; off >>= 1) m = fmaxf(m, __shfl_xor(m, off, 64));
    // all-masked row: a-m==0 -> uniform (matches jax); clamp guards exp
    float e1 = __expf(fmaxf(a1 - m, -80.f));
    float e2 = __expf(fmaxf(a2 - m, -80.f));
    float ss = e1 + e2;
    #pragma unroll
    for (int off = 32; off > 0; off >>= 1) ss += __shfl_xor(ss, off, 64);
    float inv = 1.f / ss;
    int j2 = L + 64;
    s.u2.sw.W[ii * 128 + (((L >> 3) ^ ii) << 3) + (L & 7)] = bf_rne(e1 * inv);
    s.u2.sw.W[ii * 128 + (((j2 >> 3) ^ ii) << 3) + (j2 & 7)] = bf_rne(e2 * inv);
  }
  __syncthreads();

  // ---- PV: out[i][d] = sum_j W[i,j] * h[j,d] (B from HTg prefetch) ----
  floatx4 oacc[2];
  oacc[0] = floatx4{0.f, 0.f, 0.f, 0.f};
  oacc[1] = floatx4{0.f, 0.f, 0.f, 0.f};
  #pragma unroll
  for (int kt = 0; kt < 4; ++kt) {
    int c = lq + 4 * kt;
    short8 wf = *reinterpret_cast<const short8*>(
        &s.u2.sw.W[lr * 128 + ((c ^ lr) << 3)]);
    #pragma unroll
    for (int nt = 0; nt < 2; ++nt)
      oacc[nt] = __builtin_amdgcn_mfma_f32_16x16x32_bf16(
          wf, pvb[nt][kt], oacc[nt], 0, 0, 0);
  }
  float* ob = out0 + ((size_t)b * NN + i0) * DD;
  #pragma unroll
  for (int nt = 0; nt < 2; ++nt)
    #pragma unroll
    for (int r = 0; r < 4; ++r)
      ob[(lq * 4 + r) * DD + w * 32 + nt * 16 + lr] = oacc[nt][r];
}

// 32-row attr tile, 2-deep register prefetch (named sets A/B — no runtime-
// indexed ext_vector arrays, which would spill to scratch).
__device__ __forceinline__ void attr_body(
    AttrSmem& s, const float* __restrict__ Aattr,
    const unsigned short* __restrict__ ET, float* __restrict__ out1, int tile)
{
  const int t = threadIdx.x;
  const int L = t & 63, w = t >> 6;
  const int lr = L & 15, lq = L >> 4;
  const int r0 = tile * 32;

  const int ar = t >> 3;          // A row 0..31 (8 threads per row)
  const int ak = (t & 7) * 8;     // k offset within BK (8 floats/thread)
  const int ec = t >> 1, ej0 = (t & 1) * 4;
  const float* arow = Aattr + (size_t)(r0 + ar) * AA;
  const unsigned short* erow = ET + (size_t)ec * KPAD;

  float4 pa0A, pa1A, pa0B, pa1B;
  uintx4 peA[4], peB[4];

#define ATTR_FETCH(P0, P1, PE, IT) do {                                      \
    int kb = (IT) * BK; int k4 = kb + ak;                                    \
    float4 z = {0.f, 0.f, 0.f, 0.f};                                        \
    P0 = (k4 < AA) ? *reinterpret_cast<const float4*>(arow + k4) : z;        \
    P1 = (k4 + 4 < AA) ? *reinterpret_cast<const float4*>(arow + k4 + 4) : z;\
    _Pragma("unroll")                                                        \
    for (int q = 0; q < 4; ++q)                                              \
      PE[q] = *reinterpret_cast<const uintx4*>(erow + kb + (ej0 + q) * 8);   \
  } while (0)

#define ATTR_STAGE(P0, P1, PE, BUF) do {                                     \
    uintx4 o;                                                                \
    o.x = packbf(P0.x, P0.y); o.y = packbf(P0.z, P0.w);                      \
    o.z = packbf(P1.x, P1.y); o.w = packbf(P1.z, P1.w);                      \
    int ac = t & 7;                                                          \
    *reinterpret_cast<uintx4*>(                                              \
        &s.As2[BUF][ar * BK + ((ac ^ (ar & 7)) << 3)]) = o;                  \
    _Pragma("unroll")                                                        \
    for (int q = 0; q < 4; ++q)                                              \
      *reinterpret_cast<uintx4*>(                                            \
          &s.ETs[BUF][ec * BK + (((ej0 + q) ^ (ec & 7)) << 3)]) = PE[q];     \
  } while (0)

#define ATTR_COMPUTE(BUF) do {                                               \
    _Pragma("unroll")                                                        \
    for (int ks = 0; ks < 2; ++ks) {                                         \
      int c = lq + 4 * ks;                                                   \
      short8 af[2], bf[2];                                                   \
      _Pragma("unroll")                                                      \
      for (int mt = 0; mt < 2; ++mt) {                                       \
        int row = mt * 16 + lr;                                              \
        af[mt] = *reinterpret_cast<const short8*>(                           \
            &s.As2[BUF][row * BK + ((c ^ (row & 7)) << 3)]);                 \
      }                                                                      \
      _Pragma("unroll")                                                      \
      for (int nt = 0; nt < 2; ++nt) {                                       \
        int n = w * 32 + nt * 16 + lr;                                       \
        bf[nt] = *reinterpret_cast<const short8*>(                           \
            &s.ETs[BUF][n * BK + ((c ^ (n & 7)) << 3)]);                     \
      }                                                                      \
      _Pragma("unroll")                                                      \
      for (int mt = 0; mt < 2; ++mt)                                         \
        _Pragma("unroll")                                                    \
        for (int nt = 0; nt < 2; ++nt)                                       \
          acc[mt][nt] = __builtin_amdgcn_mfma_f32_16x16x32_bf16(             \
              af[mt], bf[nt], acc[mt][nt], 0, 0, 0);                         \
    }                                                                        \
  } while (0)

  floatx4 acc[2][2];
  #pragma unroll
  for (int mt = 0; mt < 2; ++mt)
    #pragma unroll
    for (int nt = 0; nt < 2; ++nt) acc[mt][nt] = floatx4{0.f, 0.f, 0.f, 0.f};

  ATTR_FETCH(pa0A, pa1A, peA, 0);
  ATTR_FETCH(pa0B, pa1B, peB, 1);
  for (int ith = 0; ith < 8; ++ith) {
    // STAGE(buf) is only reached after the barrier proving every thread
    // finished the previous COMPUTE on that buffer.
    ATTR_STAGE(pa0A, pa1A, peA, 0);
    __syncthreads();
    if (ith < 7) ATTR_FETCH(pa0A, pa1A, peA, 2 * ith + 2);  // ~2 iters ahead
    ATTR_COMPUTE(0);
    ATTR_STAGE(pa0B, pa1B, peB, 1);
    __syncthreads();
    if (ith < 7) ATTR_FETCH(pa0B, pa1B, peB, 2 * ith + 3);
    ATTR_COMPUTE(1);
  }
#undef ATTR_FETCH
#undef ATTR_STAGE
#undef ATTR_COMPUTE

  float* ob = out1 + (size_t)r0 * DD;
  #pragma unroll
  for (int mt = 0; mt < 2; ++mt)
    #pragma unroll
    for (int nt = 0; nt < 2; ++nt)
      #pragma unroll
      for (int r = 0; r < 4; ++r)
        ob[(mt * 16 + lq * 4 + r) * DD + w * 32 + nt * 16 + lr] = acc[mt][nt][r];
}

__global__ __launch_bounds__(256, 3) void fused_kernel(
    const int* __restrict__ adj, const float* __restrict__ amat,
    const float* __restrict__ Aattr, const unsigned short* __restrict__ ET,
    const unsigned short* __restrict__ HTg, const unsigned short* __restrict__ Hg,
    float* __restrict__ out0, float* __restrict__ out1)
{
  __shared__ FusedSmem sm;
  // XCD-chunked swizzle (768 % 8 == 0 -> bijective): each XCD chunk of 96
  // wids = 64 consecutive attn tiles (8 whole batches -> L2-resident Hg/HTg)
  // + 32 attr tiles. wid%3 splits types so CU round-robin gets ~2 attn+1 attr.
  const int bid = blockIdx.x;
  const int wid = (bid & 7) * 96 + (bid >> 3);
  const int m3 = wid % 3;
  if (m3 == 2) attr_body(sm.g, Aattr, ET, out1, wid / 3);
  else         attn_body(sm.a, adj, amat, Hg, HTg, out0, (wid / 3) * 2 + m3);
}

extern "C" void kernel_launch(void* const* d_in, const int* in_sizes, int n_in,
                              void* d_out, int out_size, void* d_ws, size_t ws_size,
                              hipStream_t stream) {
  const float* hidden = (const float*)d_in[0];  // [64,128,128] fp32
  const int*   adj    = (const int*)d_in[1];    // [64,128,128] int32
  const float* amat   = (const float*)d_in[2];  // [128,4] fp32
  const float* Aattr  = (const float*)d_in[3];  // [64,128,1000] fp32
  const float* emb    = (const float*)d_in[4];  // [1000,128] fp32

  float* out0 = (float*)d_out;                  // output    [64,128,128] fp32
  float* out1 = out0 + (size_t)BB * NN * DD;    // attr_sess [64,128,128] fp32

  // d_ws layout (rebuilt every call): bf16 operand copies
  unsigned short* ET  = (unsigned short*)d_ws;      // [128][1024]
  unsigned short* HTg = ET + (size_t)DD * KPAD;     // [64][128][128] h^T
  unsigned short* Hg  = HTg + (size_t)BB * NN * DD; // [64][128][128] h (swz)

  prep_kernel<<<BB + 32, 256, 0, stream>>>(hidden, emb, ET, HTg, Hg);
  fused_kernel<<<768, 256, 0, stream>>>(adj, amat, Aattr, ET, HTg, Hg,
                                        out0, out1);
}